// Round 8
// baseline (449.163 us; speedup 1.0000x reference)
//
#include <hip/hip_runtime.h>
#include <hip/hip_fp16.h>

#define B_ 4
#define F_ 2
#define C_ 16
#define H_ 48
#define W_ 160
#define D_ 96
#define HW_ (H_*W_)
#define PIX_ 32            // pixels per block
#define GRP_ 8             // depth groups per block (PIX_*GRP_ = 256 threads)
#define BINS_ (D_/GRP_)    // 12 bins per group
#define NCHUNK_ (HW_/PIX_) // 240

__device__ __forceinline__ __half2 u2h(unsigned u) {
  return __builtin_bit_cast(__half2, u);
}

// Fused prep: mats (block 0), cur transpose+fp16, look transpose+fp16.
__global__ __launch_bounds__(256) void prep_kernel(
    const float* __restrict__ cur, const float* __restrict__ look,
    const float* __restrict__ poses, const float* __restrict__ Kmat,
    __half* __restrict__ curH, __half* __restrict__ lookH,
    float* __restrict__ mats)
{
  int tid = threadIdx.x;
  int bid = blockIdx.x;
  if (bid == 0 && tid < B_*F_) {
    int t = tid, b = t / F_;
    const float* T  = poses + t*16;
    const float* Kb = Kmat + b*16;
    float sum = 0.f;
    #pragma unroll
    for (int i = 0; i < 16; ++i) sum += T[i];
    #pragma unroll
    for (int i = 0; i < 3; ++i) {
      #pragma unroll
      for (int j = 0; j < 4; ++j) {
        float v = 0.f;
        #pragma unroll
        for (int k = 0; k < 4; ++k) v += Kb[i*4+k] * T[k*4+j];
        mats[t*16 + i*4 + j] = v;
      }
    }
    mats[t*16 + 12] = (sum != 0.f) ? 1.f : 0.f;
  }
  int idx = bid*256 + tid;
  const float* src;
  __half* dst;
  if (idx < B_*HW_) {
    int hw = idx % HW_, s = idx / HW_;
    src = cur + (size_t)s*C_*HW_ + hw;
    dst = curH + (size_t)idx*C_;
  } else {
    int j = idx - B_*HW_;            // 0 .. B*F*HW-1
    int hw = j % HW_, s = j / HW_;
    src = look + (size_t)s*C_*HW_ + hw;
    dst = lookH + (size_t)j*C_;
  }
  __half2 h[8];
  #pragma unroll
  for (int c = 0; c < 8; ++c)
    h[c] = __floats2half2_rn(src[(size_t)(2*c)*HW_], src[(size_t)(2*c+1)*HW_]);
  uint4* o = reinterpret_cast<uint4*>(dst);
  o[0] = *reinterpret_cast<uint4*>(&h[0]);
  o[1] = *reinterpret_cast<uint4*>(&h[4]);
}

// Fused cost + finalize. Block = 32 pixels x 8 depth-groups (12 bins each).
// Frame-outer / depth-inner with tap-quad reuse held in NAMED registers
// (t0..t7); taps accessed via value-level bit-casts of uint4 members
// (round-7 lesson: never span named variables with a pointer).
__global__ __launch_bounds__(256, 4) void fused_kernel(
    const __half* __restrict__ curH, const __half* __restrict__ lookH,
    const float* __restrict__ mats, const float* __restrict__ invK,
    const float* __restrict__ dbins,
    float* __restrict__ cost, float* __restrict__ missing)
{
  int tid = threadIdx.x;
  int pix = tid & (PIX_-1);
  int grp = tid >> 5;                 // 0..7
  int bid = blockIdx.x;
  int chunk = bid % NCHUNK_;
  int b = bid / NCHUNK_;
  int hw = chunk*PIX_ + pix;
  int x = hw % W_, y = hw / W_;
  size_t obase = ((size_t)(b*D_ + grp*BINS_))*HW_ + hw;

  float res[BINS_];
  #pragma unroll
  for (int dd = 0; dd < BINS_; ++dd) res[dd] = 0.f;
  float lmax = 0.f;
  bool interior = (x >= 2 && x < W_-2 && y >= 2 && y < H_-2);
  if (interior) {
    const float* iK = invK + b*16;
    float xf = (float)x, yf = (float)y;
    float r0 = iK[0]*xf + iK[1]*yf + iK[2];
    float r1 = iK[4]*xf + iK[5]*yf + iK[6];
    float r2 = iK[8]*xf + iK[9]*yf + iK[10];
    __half2 cc2[8];
    {
      const uint4* cur4 = reinterpret_cast<const uint4*>(curH + (size_t)(b*HW_ + hw)*C_);
      *reinterpret_cast<uint4*>(&cc2[0]) = cur4[0];
      *reinterpret_cast<uint4*>(&cc2[4]) = cur4[1];
    }
    float dep[BINS_];
    #pragma unroll
    for (int dd = 0; dd < BINS_; ++dd) dep[dd] = dbins[grp*BINS_ + dd];

    float diffs0[BINS_];
    #pragma unroll
    for (int f = 0; f < F_; ++f) {
      const float* Mt = mats + (b*F_+f)*16;
      float M0=Mt[0], M1=Mt[1], M2 =Mt[2],  M3 =Mt[3];
      float M4=Mt[4], M5=Mt[5], M6 =Mt[6],  M7 =Mt[7];
      float M8=Mt[8], M9=Mt[9], M10=Mt[10], M11=Mt[11];
      float valid = Mt[12];
      const __half* fbase = lookH + (size_t)((b*F_+f)*HW_)*C_;
      int prev_off = -1;
      uint4 t0 = make_uint4(0,0,0,0), t1 = t0, t2 = t0, t3 = t0;
      uint4 t4 = t0, t5 = t0, t6 = t0, t7 = t0;
      #pragma unroll
      for (int dd = 0; dd < BINS_; ++dd) {
        float p0 = dep[dd]*r0, p1 = dep[dd]*r1, p2 = dep[dd]*r2;
        float camx = M0*p0 + M1*p1 + M2 *p2 + M3;
        float camy = M4*p0 + M5*p1 + M6 *p2 + M7;
        float camz = M8*p0 + M9*p1 + M10*p2 + M11;
        float z  = camz + 1e-7f;
        float px = camx / z;
        float py = camy / z;
        bool ok = (valid != 0.f) && (px >= 2.f) && (px <= (float)(W_-2))
                                 && (py >= 2.f) && (py <= (float)(H_-2));
        float x0 = floorf(px), y0 = floorf(py);
        float fx = px - x0, fy = py - y0;
        fx = fminf(fmaxf(fx, 0.f), 1.f);
        fy = fminf(fmaxf(fy, 0.f), 1.f);
        int xi = min(max((int)x0, 0), W_-2);
        int yi = min(max((int)y0, 0), H_-2);
        int off = (yi*W_ + xi)*C_;
        if (off != prev_off) {   // same quad as previous bin -> taps unchanged
          const uint4* rr0 = reinterpret_cast<const uint4*>(fbase + off);
          const uint4* rr1 = reinterpret_cast<const uint4*>(fbase + off + W_*C_);
          t0 = rr0[0]; t1 = rr0[1]; t2 = rr0[2]; t3 = rr0[3];
          t4 = rr1[0]; t5 = rr1[1]; t6 = rr1[2]; t7 = rr1[3];
          prev_off = off;
        }
        __half2 w00h = __float2half2_rn((1.f-fx)*(1.f-fy));
        __half2 w10h = __float2half2_rn(fx*(1.f-fy));
        __half2 w01h = __float2half2_rn((1.f-fx)*fy);
        __half2 w11h = __float2half2_rn(fx*fy);
        __half2 acc0 = __float2half2_rn(0.f);
        __half2 acc1 = __float2half2_rn(0.f);
        // Exact replication of round-5 order: i=0..7 over half2 channels,
        // even i -> acc0, odd i -> acc1. Channels 0-7: t0/t2/t4/t6;
        // channels 8-15: t1/t3/t5/t7. All value-level, no addressing.
        #define TAP_(u00,u10,u01,u11,ccv,acc) { \
          __half2 v = __hmul2(w00h, u2h(u00)); \
          v = __hfma2(w10h, u2h(u10), v); \
          v = __hfma2(w01h, u2h(u01), v); \
          v = __hfma2(w11h, u2h(u11), v); \
          acc = __hadd2(acc, __habs2(__hsub2(v, ccv))); }
        TAP_(t0.x, t2.x, t4.x, t6.x, cc2[0], acc0)
        TAP_(t0.y, t2.y, t4.y, t6.y, cc2[1], acc1)
        TAP_(t0.z, t2.z, t4.z, t6.z, cc2[2], acc0)
        TAP_(t0.w, t2.w, t4.w, t6.w, cc2[3], acc1)
        TAP_(t1.x, t3.x, t5.x, t7.x, cc2[4], acc0)
        TAP_(t1.y, t3.y, t5.y, t7.y, cc2[5], acc1)
        TAP_(t1.z, t3.z, t5.z, t7.z, cc2[6], acc0)
        TAP_(t1.w, t3.w, t5.w, t7.w, cc2[7], acc1)
        #undef TAP_
        float2 f0 = __half22float2(acc0);
        float2 f1 = __half22float2(acc1);
        float s = (f0.x + f0.y) + (f1.x + f1.y);
        float diffs = s * (1.f/16.f);
        diffs = ok ? diffs : 0.f;
        if (f == 0) {
          diffs0[dd] = diffs;
        } else {
          float c0 = diffs0[dd];
          float cnt = ((c0 > 0.f) ? 1.f : 0.f) + ((diffs > 0.f) ? 1.f : 0.f);
          float r = (c0 + diffs) / (cnt + 1e-7f);
          res[dd] = r;
          lmax = fmaxf(lmax, r);
        }
      }
    }
  }

  // per-pixel max over the 8 depth-groups
  __shared__ float lmaxs[GRP_][PIX_];
  lmaxs[grp][pix] = lmax;
  __syncthreads();
  float pmax = lmaxs[0][pix];
  #pragma unroll
  for (int g = 1; g < GRP_; ++g) pmax = fmaxf(pmax, lmaxs[g][pix]);

  // write cost (missing-filled) + missing, straight from registers
  #pragma unroll
  for (int dd = 0; dd < BINS_; ++dd) {
    size_t o = obase + (size_t)dd*HW_;
    float v = res[dd];
    float miss = (v == 0.f) ? 1.f : 0.f;
    cost[o]    = miss ? pmax : v;
    missing[o] = miss;
  }
}

extern "C" void kernel_launch(void* const* d_in, const int* in_sizes, int n_in,
                              void* d_out, int out_size, void* d_ws, size_t ws_size,
                              hipStream_t stream) {
  const float* cur   = (const float*)d_in[0];
  const float* look  = (const float*)d_in[1];
  const float* poses = (const float*)d_in[2];
  const float* Km    = (const float*)d_in[3];
  const float* invK  = (const float*)d_in[4];
  const float* dbins = (const float*)d_in[5];

  float* out_cost = (float*)d_out;
  float* out_miss = out_cost + (size_t)B_*D_*HW_;

  char*   ws    = (char*)d_ws;
  float*  mats  = (float*)ws;                                       // 128 floats
  __half* curH  = (__half*)(ws + 1024);                             // B*HW*C f16
  __half* lookH = (__half*)(ws + 1024 + (size_t)B_*HW_*C_*2);       // B*F*HW*C f16

  prep_kernel<<<(B_*HW_ + B_*F_*HW_)/256, 256, 0, stream>>>(
      cur, look, poses, Km, curH, lookH, mats);
  fused_kernel<<<B_*NCHUNK_, 256, 0, stream>>>(
      curH, lookH, mats, invK, dbins, out_cost, out_miss);
}

// Round 9
// 41.633 us; speedup vs baseline: 10.7886x; 10.7886x over previous
//
#include <hip/hip_runtime.h>
#include <hip/hip_fp16.h>

#define B_ 4
#define F_ 2
#define C_ 16
#define H_ 48
#define W_ 160
#define D_ 96
#define HW_ (H_*W_)
#define PIX_ 64            // pixels per block (= lanes per wave: whole wave shares one depth-group)
#define GRP_ 8             // depth groups per block (PIX_*GRP_ = 512 threads)
#define BINS_ (D_/GRP_)    // 12 bins per group
#define NCHUNK_ (HW_/PIX_) // 120

// Fused prep: mats (block 0), cur transpose+fp16, look transpose+fp16.
__global__ __launch_bounds__(256) void prep_kernel(
    const float* __restrict__ cur, const float* __restrict__ look,
    const float* __restrict__ poses, const float* __restrict__ Kmat,
    __half* __restrict__ curH, __half* __restrict__ lookH,
    float* __restrict__ mats)
{
  int tid = threadIdx.x;
  int bid = blockIdx.x;
  if (bid == 0 && tid < B_*F_) {
    int t = tid, b = t / F_;
    const float* T  = poses + t*16;
    const float* Kb = Kmat + b*16;
    float sum = 0.f;
    #pragma unroll
    for (int i = 0; i < 16; ++i) sum += T[i];
    #pragma unroll
    for (int i = 0; i < 3; ++i) {
      #pragma unroll
      for (int j = 0; j < 4; ++j) {
        float v = 0.f;
        #pragma unroll
        for (int k = 0; k < 4; ++k) v += Kb[i*4+k] * T[k*4+j];
        mats[t*16 + i*4 + j] = v;
      }
    }
    mats[t*16 + 12] = (sum != 0.f) ? 1.f : 0.f;
  }
  int idx = bid*256 + tid;
  const float* src;
  __half* dst;
  if (idx < B_*HW_) {
    int hw = idx % HW_, s = idx / HW_;
    src = cur + (size_t)s*C_*HW_ + hw;
    dst = curH + (size_t)idx*C_;
  } else {
    int j = idx - B_*HW_;            // 0 .. B*F*HW-1
    int hw = j % HW_, s = j / HW_;
    src = look + (size_t)s*C_*HW_ + hw;
    dst = lookH + (size_t)j*C_;
  }
  __half2 h[8];
  #pragma unroll
  for (int c = 0; c < 8; ++c)
    h[c] = __floats2half2_rn(src[(size_t)(2*c)*HW_], src[(size_t)(2*c+1)*HW_]);
  uint4* o = reinterpret_cast<uint4*>(dst);
  o[0] = *reinterpret_cast<uint4*>(&h[0]);
  o[1] = *reinterpret_cast<uint4*>(&h[4]);
}

// Fused cost + finalize. Block = 64 pixels x 8 depth-groups (12 bins each).
// Each WAVE = 64 consecutive pixels at one depth-group -> full-wave
// cache-line sharing on the bilinear gathers. Body identical to round 5
// (unconditional batched loads; no loop-carried conditional state).
__global__ __launch_bounds__(512, 4) void fused_kernel(
    const __half* __restrict__ curH, const __half* __restrict__ lookH,
    const float* __restrict__ mats, const float* __restrict__ invK,
    const float* __restrict__ dbins,
    float* __restrict__ cost, float* __restrict__ missing)
{
  int tid = threadIdx.x;
  int pix = tid & (PIX_-1);
  int grp = tid >> 6;                 // 0..7 (wave index)
  int bid = blockIdx.x;
  int chunk = bid % NCHUNK_;
  int b = bid / NCHUNK_;
  int hw = chunk*PIX_ + pix;
  int x = hw % W_, y = hw / W_;
  size_t obase = ((size_t)(b*D_ + grp*BINS_))*HW_ + hw;

  float res[BINS_];
  #pragma unroll
  for (int dd = 0; dd < BINS_; ++dd) res[dd] = 0.f;
  float lmax = 0.f;
  bool interior = (x >= 2 && x < W_-2 && y >= 2 && y < H_-2);
  if (interior) {
    const float* iK = invK + b*16;
    float xf = (float)x, yf = (float)y;
    float r0 = iK[0]*xf + iK[1]*yf + iK[2];
    float r1 = iK[4]*xf + iK[5]*yf + iK[6];
    float r2 = iK[8]*xf + iK[9]*yf + iK[10];
    __half2 cc2[8];
    {
      const uint4* cur4 = reinterpret_cast<const uint4*>(curH + (size_t)(b*HW_ + hw)*C_);
      *reinterpret_cast<uint4*>(&cc2[0]) = cur4[0];
      *reinterpret_cast<uint4*>(&cc2[4]) = cur4[1];
    }
    // wave-uniform projection rows (b uniform per block, f static)
    float Mv[2][13];
    #pragma unroll
    for (int f = 0; f < F_; ++f) {
      const float* Mt = mats + (b*F_+f)*16;
      #pragma unroll
      for (int i = 0; i < 13; ++i) Mv[f][i] = Mt[i];
    }
    #pragma unroll
    for (int dd = 0; dd < BINS_; ++dd) {
      float dep = dbins[grp*BINS_ + dd];
      float p0 = dep*r0, p1 = dep*r1, p2 = dep*r2;
      // --- phase 1: addresses + weights for both frames ---
      const __half* bases[F_];
      float w00f[F_], w10f[F_], w01f[F_], w11f[F_];
      bool okf[F_];
      #pragma unroll
      for (int f = 0; f < F_; ++f) {
        float camx = Mv[f][0]*p0 + Mv[f][1]*p1 + Mv[f][2] *p2 + Mv[f][3];
        float camy = Mv[f][4]*p0 + Mv[f][5]*p1 + Mv[f][6] *p2 + Mv[f][7];
        float camz = Mv[f][8]*p0 + Mv[f][9]*p1 + Mv[f][10]*p2 + Mv[f][11];
        float z  = camz + 1e-7f;
        float px = camx / z;
        float py = camy / z;
        okf[f] = (Mv[f][12] != 0.f) && (px >= 2.f) && (px <= (float)(W_-2))
                                    && (py >= 2.f) && (py <= (float)(H_-2));
        float x0 = floorf(px), y0 = floorf(py);
        float fx = px - x0, fy = py - y0;
        fx = fminf(fmaxf(fx, 0.f), 1.f);
        fy = fminf(fmaxf(fy, 0.f), 1.f);
        int xi = min(max((int)x0, 0), W_-2);
        int yi = min(max((int)y0, 0), H_-2);
        bases[f] = lookH + ((size_t)((b*F_+f)*HW_) + yi*W_ + xi)*C_;
        w00f[f] = (1.f-fx)*(1.f-fy); w10f[f] = fx*(1.f-fy);
        w01f[f] = (1.f-fx)*fy;       w11f[f] = fx*fy;
      }
      // --- phase 2: issue all 16 tap loads ---
      uint4 t[16];
      #pragma unroll
      for (int f = 0; f < F_; ++f) {
        const uint4* rr0 = reinterpret_cast<const uint4*>(bases[f]);
        const uint4* rr1 = reinterpret_cast<const uint4*>(bases[f] + W_*C_);
        #pragma unroll
        for (int i = 0; i < 4; ++i) t[f*8+i]   = rr0[i];
        #pragma unroll
        for (int i = 0; i < 4; ++i) t[f*8+4+i] = rr1[i];
      }
      // --- phase 3: fp16 interpolation + L1 diff ---
      float costsum = 0.f, cnt = 0.f;
      #pragma unroll
      for (int f = 0; f < F_; ++f) {
        __half2 w00h = __float2half2_rn(w00f[f]);
        __half2 w10h = __float2half2_rn(w10f[f]);
        __half2 w01h = __float2half2_rn(w01f[f]);
        __half2 w11h = __float2half2_rn(w11f[f]);
        const __half2* a00 = reinterpret_cast<const __half2*>(&t[f*8+0]);
        const __half2* a10 = reinterpret_cast<const __half2*>(&t[f*8+2]);
        const __half2* a01 = reinterpret_cast<const __half2*>(&t[f*8+4]);
        const __half2* a11 = reinterpret_cast<const __half2*>(&t[f*8+6]);
        __half2 acc0 = __float2half2_rn(0.f);
        __half2 acc1 = __float2half2_rn(0.f);
        #pragma unroll
        for (int i = 0; i < 8; ++i) {
          __half2 v = __hmul2(w00h, a00[i]);
          v = __hfma2(w10h, a10[i], v);
          v = __hfma2(w01h, a01[i], v);
          v = __hfma2(w11h, a11[i], v);
          __half2 dsub = __habs2(__hsub2(v, cc2[i]));
          if (i & 1) acc1 = __hadd2(acc1, dsub);
          else       acc0 = __hadd2(acc0, dsub);
        }
        float2 f0 = __half22float2(acc0);
        float2 f1 = __half22float2(acc1);
        float s = (f0.x + f0.y) + (f1.x + f1.y);
        float diffs = s * (1.f/16.f);
        diffs = okf[f] ? diffs : 0.f;
        costsum += diffs;
        cnt     += (diffs > 0.f) ? 1.f : 0.f;
      }
      float r = costsum / (cnt + 1e-7f);
      res[dd] = r;
      lmax = fmaxf(lmax, r);
    }
  }

  // per-pixel max over the 8 depth-groups
  __shared__ float lmaxs[GRP_][PIX_];
  lmaxs[grp][pix] = lmax;
  __syncthreads();
  float pmax = lmaxs[0][pix];
  #pragma unroll
  for (int g = 1; g < GRP_; ++g) pmax = fmaxf(pmax, lmaxs[g][pix]);

  // write cost (missing-filled) + missing, straight from registers
  #pragma unroll
  for (int dd = 0; dd < BINS_; ++dd) {
    size_t o = obase + (size_t)dd*HW_;
    float v = res[dd];
    float miss = (v == 0.f) ? 1.f : 0.f;
    cost[o]    = miss ? pmax : v;
    missing[o] = miss;
  }
}

extern "C" void kernel_launch(void* const* d_in, const int* in_sizes, int n_in,
                              void* d_out, int out_size, void* d_ws, size_t ws_size,
                              hipStream_t stream) {
  const float* cur   = (const float*)d_in[0];
  const float* look  = (const float*)d_in[1];
  const float* poses = (const float*)d_in[2];
  const float* Km    = (const float*)d_in[3];
  const float* invK  = (const float*)d_in[4];
  const float* dbins = (const float*)d_in[5];

  float* out_cost = (float*)d_out;
  float* out_miss = out_cost + (size_t)B_*D_*HW_;

  char*   ws    = (char*)d_ws;
  float*  mats  = (float*)ws;                                       // 128 floats
  __half* curH  = (__half*)(ws + 1024);                             // B*HW*C f16
  __half* lookH = (__half*)(ws + 1024 + (size_t)B_*HW_*C_*2);       // B*F*HW*C f16

  prep_kernel<<<(B_*HW_ + B_*F_*HW_)/256, 256, 0, stream>>>(
      cur, look, poses, Km, curH, lookH, mats);
  fused_kernel<<<B_*NCHUNK_, 512, 0, stream>>>(
      curH, lookH, mats, invK, dbins, out_cost, out_miss);
}